// Round 6
// baseline (125.382 us; speedup 1.0000x reference)
//
#include <hip/hip_runtime.h>

#define EPS 1e-5f

typedef float v2f __attribute__((ext_vector_type(2)));

// Fast reciprocal: single v_rcp_f32 (~1 ulp) instead of IEEE div sequence.
__device__ __forceinline__ float frcp(float x) { return __builtin_amdgcn_rcpf(x); }
__device__ __forceinline__ float fsigm(float x) { return frcp(1.0f + __expf(-x)); }
__device__ __forceinline__ float ftanh(float x) {
    float e = __expf(-2.0f * x);
    return (1.0f - e) * frcp(1.0f + e);
}
// uniform broadcast of lane (32+k)'s value -> SGPR (k compile-time constant)
__device__ __forceinline__ float rdl32(float v, int k) {
    return __int_as_float(__builtin_amdgcn_readlane(__float_as_int(v), 32 + k));
}
// Sum of lane m and lane m+32's values, replicated to both halves (semantics-
// agnostic use of permlane32_swap: sum of both outputs = x[m]+x[m+32]).
__device__ __forceinline__ float xhalf_sum(float x) {
#if __has_builtin(__builtin_amdgcn_permlane32_swap)
    auto r = __builtin_amdgcn_permlane32_swap(__float_as_uint(x),
                                              __float_as_uint(x), false, false);
    return __uint_as_float(r[0]) + __uint_as_float(r[1]);
#else
    return x + __shfl_xor(x, 32);
#endif
}

// ---------------------------------------------------------------------------
// Kernel 1: per-frame frontend (MLP 63->63->64 + LayerNorm) and input-side
// gate projection Gx[t] = f_t @ w_ih.T + b_ih + b_hh.  One block per frame.
// (Proven round-1 body, absmax 0 — unchanged for attribution.)
// ---------------------------------------------------------------------------
__global__ __launch_bounds__(64) void frontend_kernel(
    const float* __restrict__ x,
    const float* __restrict__ w00, const float* __restrict__ b00,
    const float* __restrict__ w01, const float* __restrict__ b01,
    const float* __restrict__ ln_g, const float* __restrict__ ln_b,
    const float* __restrict__ w_ih,
    const float* __restrict__ b_ih, const float* __restrict__ b_hh,
    float* __restrict__ Gx)
{
    __shared__ float smem[16324];
    float* w00s = smem;          // [63*63] rows stride 63 (conflict-free)
    float* w01s = smem + 3972;   // [64*63]
    float* wihT = smem + 8004;   // [64][128] transposed w_ih
    float* scr  = smem + 16196;  // [128]

    const int j = threadIdx.x;
    const int t = blockIdx.x;

    {
        const float4* g4 = (const float4*)w00;
        float4* s4 = (float4*)w00s;
        for (int i = j; i < 992; i += 64) s4[i] = g4[i];
        if (j == 0) w00s[3968] = w00[3968];
    }
    {
        const float4* g4 = (const float4*)w01;
        float4* s4 = (float4*)w01s;
        for (int i = j; i < 1008; i += 64) s4[i] = g4[i];
    }
    for (int r = j; r < 128; r += 64) {
        const float4* row = (const float4*)(w_ih + r * 64);
        #pragma unroll
        for (int q = 0; q < 16; q++) {
            float4 v = row[q];
            wihT[(4 * q + 0) * 128 + r] = v.x;
            wihT[(4 * q + 1) * 128 + r] = v.y;
            wihT[(4 * q + 2) * 128 + r] = v.z;
            wihT[(4 * q + 3) * 128 + r] = v.w;
        }
    }
    scr[j] = (j < 63) ? x[t * 63 + j] : 0.0f;
    __syncthreads();

    float f0 = 0.0f;
    if (j < 63) {
        float acc = b00[j];
        const float* wr = w00s + j * 63;
        #pragma unroll
        for (int k = 0; k < 63; k++) acc += scr[k] * wr[k];
        f0 = fmaxf(acc, 0.0f);
    }
    __syncthreads();
    scr[j] = f0;
    __syncthreads();

    float acc = b01[j];
    {
        const float* wr = w01s + j * 63;
        #pragma unroll
        for (int k = 0; k < 63; k++) acc += scr[k] * wr[k];
    }
    float f1 = fmaxf(acc, 0.0f);

    float s = f1, sq = f1 * f1;
    #pragma unroll
    for (int off = 32; off > 0; off >>= 1) {
        s  += __shfl_xor(s, off);
        sq += __shfl_xor(sq, off);
    }
    float mu  = s * (1.0f / 64.0f);
    float var = sq * (1.0f / 64.0f) - mu * mu;
    float f   = (f1 - mu) * rsqrtf(var + EPS) * ln_g[j] + ln_b[j];
    __syncthreads();
    scr[64 + j] = f;
    __syncthreads();

    float a0 = b_ih[j] + b_hh[j];
    float a1 = b_ih[j + 64] + b_hh[j + 64];
    #pragma unroll
    for (int k = 0; k < 64; k++) {
        float fk = scr[64 + k];
        a0 += fk * wihT[k * 128 + j];
        a1 += fk * wihT[k * 128 + 64 + j];
    }
    Gx[t * 128 + j]      = a0;
    Gx[t * 128 + 64 + j] = a1;
}

// ---------------------------------------------------------------------------
// Kernel 2: single-wave LSTM scan + head.
// This round: (a) ALL 32 h-broadcast readlanes hoisted into a batch before
// the FMA block -- breaks the per-pair VALU-writes-SGPR -> VALU-reads-SGPR
// hazard serialization of the interleaved form; (b) gate FMAs as explicit
// v2f ext-vectors -> v_pk_fma_f32 with the SGPR h as broadcast operand
// (64 fma -> 32 pk_fma); (c) sigm(a1)/tanh(a1) share one exp via e2=e*e.
// ---------------------------------------------------------------------------
__global__ __launch_bounds__(64) void scan_kernel(
    const float* __restrict__ Gx,
    const float* __restrict__ w_hh,
    const float* __restrict__ bn_g, const float* __restrict__ bn_b,
    const float* __restrict__ w10, const float* __restrict__ b10,
    const float* __restrict__ w11, const float* __restrict__ b11,
    const float* __restrict__ w12, const float* __restrict__ b12,
    float* __restrict__ out)
{
    __shared__ float gxs[7808];  // 61*128 (frame 60 = pad for prefetch)
    const int j = threadIdx.x;

    // wAB[k] = {w_hh[j][k], w_hh[j+64][k]}
    v2f wAB[32];
    {
        const float4* r0 = (const float4*)(w_hh + j * 32);
        const float4* r1 = (const float4*)(w_hh + (j + 64) * 32);
        #pragma unroll
        for (int q = 0; q < 8; q++) {
            float4 a = r0[q];
            float4 b = r1[q];
            wAB[4 * q + 0] = (v2f){a.x, b.x};
            wAB[4 * q + 1] = (v2f){a.y, b.y};
            wAB[4 * q + 2] = (v2f){a.z, b.z};
            wAB[4 * q + 3] = (v2f){a.w, b.w};
        }
    }
    // stage Gx -> LDS (1920 float4) + zero pad frame
    {
        const float4* g4 = (const float4*)Gx;
        float4* s4 = (float4*)gxs;
        for (int i = j; i < 1920; i += 64) s4[i] = g4[i];
        gxs[7680 + j] = 0.0f;
        gxs[7744 + j] = 0.0f;
    }
    __syncthreads();

    const bool low = (j < 32);
    float c = 0.0f, hn = 0.0f;
    float gA = gxs[j], gB = gxs[64 + j];
    for (int t = 0; t < 60; t++) {
        // (a) batch ALL readlanes first -- hazards overlap instead of
        // serializing against their consumer FMAs.
        float hk[32];
        #pragma unroll
        for (int k = 0; k < 32; k++) hk[k] = rdl32(hn, k);

        v2f acc0 = {gA, gB};
        v2f acc1 = {0.f, 0.f};
        v2f acc2 = {0.f, 0.f};
        v2f acc3 = {0.f, 0.f};
        gA = gxs[(t + 1) * 128 + j];
        gB = gxs[(t + 1) * 128 + 64 + j];
        #pragma unroll
        for (int d = 0; d < 8; d++) {
            int k = d * 4;
            v2f h0 = {hk[k + 0], hk[k + 0]};
            v2f h1 = {hk[k + 1], hk[k + 1]};
            v2f h2 = {hk[k + 2], hk[k + 2]};
            v2f h3 = {hk[k + 3], hk[k + 3]};
            acc0 += h0 * wAB[k + 0];
            acc1 += h1 * wAB[k + 1];
            acc2 += h2 * wAB[k + 2];
            acc3 += h3 * wAB[k + 3];
        }
        v2f asum = (acc0 + acc1) + (acc2 + acc3);
        float a0 = asum.x;  // low: i_m ; high: f_m
        float a1 = asum.y;  // low: g_m ; high: o_m

        // (c) shared exp: sigm(a1) and tanh(a1) from one exp(-a1)
        float e1 = __expf(-a1);
        float sO = frcp(1.0f + e1);                 // high: sigm(o)
        float e2 = e1 * e1;                         // exp(-2*a1)
        float t1 = (1.0f - e2) * frcp(1.0f + e2);   // low: tanh(g)
        float s0 = fsigm(a0);                       // low: sigm(i); high: sigm(f)
        float own = s0 * (low ? t1 : c);
        c = xhalf_sum(own);          // sigm(i)tanh(g) + sigm(f)*c, all lanes
        hn = sO * ftanh(c);          // valid on high lanes
    }

    // Head (h read from HIGH lanes; lanes >=32 replicate rows 0..31)
    const float rs = rsqrtf(1.0f + EPS);
    const int ro = j & 31;
    float acc = b10[ro];
    #pragma unroll
    for (int k = 0; k < 32; k++) {
        float hkk = rdl32(hn, k);
        float hb = hkk * rs * bn_g[k] + bn_b[k];
        acc += w10[ro * 32 + k] * hb;
    }
    float o1 = fmaxf(acc, 0.0f);

    acc = b11[ro];
    #pragma unroll
    for (int k = 0; k < 32; k++)
        acc += w11[ro * 32 + k]
             * __int_as_float(__builtin_amdgcn_readlane(__float_as_int(o1), k));
    float o2 = fmaxf(acc, 0.0f);

    float a[4];
    #pragma unroll
    for (int r = 0; r < 4; r++) a[r] = b12[j + 64 * r];
    #pragma unroll
    for (int k = 0; k < 32; k++) {
        float h2 = __int_as_float(__builtin_amdgcn_readlane(__float_as_int(o2), k));
        #pragma unroll
        for (int r = 0; r < 4; r++) a[r] += w12[(j + 64 * r) * 32 + k] * h2;
    }
    #pragma unroll
    for (int r = 0; r < 4; r++) out[j + 64 * r] = a[r];
}

extern "C" void kernel_launch(void* const* d_in, const int* in_sizes, int n_in,
                              void* d_out, int out_size, void* d_ws, size_t ws_size,
                              hipStream_t stream) {
    const float* x    = (const float*)d_in[0];
    const float* w00  = (const float*)d_in[1];
    const float* b00  = (const float*)d_in[2];
    const float* w01  = (const float*)d_in[3];
    const float* b01  = (const float*)d_in[4];
    const float* ln_g = (const float*)d_in[5];
    const float* ln_b = (const float*)d_in[6];
    const float* w_ih = (const float*)d_in[7];
    const float* w_hh = (const float*)d_in[8];
    const float* b_ih = (const float*)d_in[9];
    const float* b_hh = (const float*)d_in[10];
    const float* bn_g = (const float*)d_in[11];
    const float* bn_b = (const float*)d_in[12];
    const float* w10  = (const float*)d_in[13];
    const float* b10  = (const float*)d_in[14];
    const float* w11  = (const float*)d_in[15];
    const float* b11  = (const float*)d_in[16];
    const float* w12  = (const float*)d_in[17];
    const float* b12  = (const float*)d_in[18];
    float* out = (float*)d_out;
    float* Gx  = (float*)d_ws;  // 30,720 B

    frontend_kernel<<<60, 64, 0, stream>>>(x, w00, b00, w01, b01, ln_g, ln_b,
                                           w_ih, b_ih, b_hh, Gx);
    scan_kernel<<<1, 64, 0, stream>>>(Gx, w_hh, bn_g, bn_b, w10, b10,
                                      w11, b11, w12, b12, out);
}

// Round 7
// 124.474 us; speedup vs baseline: 1.0073x; 1.0073x over previous
//
#include <hip/hip_runtime.h>

#define EPS 1e-5f
#define MAGIC 0x5CA9F1A6u

typedef float v2f __attribute__((ext_vector_type(2)));

// Fast reciprocal: single v_rcp_f32 (~1 ulp) instead of IEEE div sequence.
__device__ __forceinline__ float frcp(float x) { return __builtin_amdgcn_rcpf(x); }
__device__ __forceinline__ float fsigm(float x) { return frcp(1.0f + __expf(-x)); }
__device__ __forceinline__ float ftanh(float x) {
    float e = __expf(-2.0f * x);
    return (1.0f - e) * frcp(1.0f + e);
}
// uniform broadcast of lane (32+k)'s value -> SGPR (k compile-time constant)
__device__ __forceinline__ float rdl32(float v, int k) {
    return __int_as_float(__builtin_amdgcn_readlane(__float_as_int(v), 32 + k));
}
// Sum of lane m and lane m+32's values, replicated to both halves (semantics-
// agnostic use of permlane32_swap: sum of both outputs = x[m]+x[m+32]).
__device__ __forceinline__ float xhalf_sum(float x) {
#if __has_builtin(__builtin_amdgcn_permlane32_swap)
    auto r = __builtin_amdgcn_permlane32_swap(__float_as_uint(x),
                                              __float_as_uint(x), false, false);
    return __uint_as_float(r[0]) + __uint_as_float(r[1]);
#else
    return x + __shfl_xor(x, 32);
#endif
}

// ---------------------------------------------------------------------------
// Single launch. Blocks 0..59: per-frame frontend (proven body) ->
// Gx store -> threadfence -> release flag (proven R2 path).
// Block 60: stage w_hh while frontends run, PARALLEL-poll the 60 flags
// (lane t polls flags[t], relaxed agent loads = L1-bypass, one ballot per
// sweep), one acquire load for ordering, then the proven scan + head.
// ---------------------------------------------------------------------------
__global__ __launch_bounds__(64) void fused_kernel(
    const float* __restrict__ x,
    const float* __restrict__ w00, const float* __restrict__ b00,
    const float* __restrict__ w01, const float* __restrict__ b01,
    const float* __restrict__ ln_g, const float* __restrict__ ln_b,
    const float* __restrict__ w_ih, const float* __restrict__ w_hh,
    const float* __restrict__ b_ih, const float* __restrict__ b_hh,
    const float* __restrict__ bn_g, const float* __restrict__ bn_b,
    const float* __restrict__ w10, const float* __restrict__ b10,
    const float* __restrict__ w11, const float* __restrict__ b11,
    const float* __restrict__ w12, const float* __restrict__ b12,
    float* __restrict__ Gx, unsigned* __restrict__ flags,
    float* __restrict__ out)
{
    __shared__ float smem[16324];
    const int j = threadIdx.x;

    if (blockIdx.x < 60) {
        // ------------------- frontend (proven round-1 body) -------------------
        const int t = blockIdx.x;
        float* w00s = smem;          // [63*63] rows stride 63 (conflict-free)
        float* w01s = smem + 3972;   // [64*63]
        float* wihT = smem + 8004;   // [64][128] transposed w_ih
        float* scr  = smem + 16196;  // [128]

        {
            const float4* g4 = (const float4*)w00;
            float4* s4 = (float4*)w00s;
            for (int i = j; i < 992; i += 64) s4[i] = g4[i];
            if (j == 0) w00s[3968] = w00[3968];
        }
        {
            const float4* g4 = (const float4*)w01;
            float4* s4 = (float4*)w01s;
            for (int i = j; i < 1008; i += 64) s4[i] = g4[i];
        }
        for (int r = j; r < 128; r += 64) {
            const float4* row = (const float4*)(w_ih + r * 64);
            #pragma unroll
            for (int q = 0; q < 16; q++) {
                float4 v = row[q];
                wihT[(4 * q + 0) * 128 + r] = v.x;
                wihT[(4 * q + 1) * 128 + r] = v.y;
                wihT[(4 * q + 2) * 128 + r] = v.z;
                wihT[(4 * q + 3) * 128 + r] = v.w;
            }
        }
        scr[j] = (j < 63) ? x[t * 63 + j] : 0.0f;
        __syncthreads();

        float f0 = 0.0f;
        if (j < 63) {
            float acc = b00[j];
            const float* wr = w00s + j * 63;
            #pragma unroll
            for (int k = 0; k < 63; k++) acc += scr[k] * wr[k];
            f0 = fmaxf(acc, 0.0f);
        }
        __syncthreads();
        scr[j] = f0;
        __syncthreads();

        float acc = b01[j];
        {
            const float* wr = w01s + j * 63;
            #pragma unroll
            for (int k = 0; k < 63; k++) acc += scr[k] * wr[k];
        }
        float f1 = fmaxf(acc, 0.0f);

        float s = f1, sq = f1 * f1;
        #pragma unroll
        for (int off = 32; off > 0; off >>= 1) {
            s  += __shfl_xor(s, off);
            sq += __shfl_xor(sq, off);
        }
        float mu  = s * (1.0f / 64.0f);
        float var = sq * (1.0f / 64.0f) - mu * mu;
        float f   = (f1 - mu) * rsqrtf(var + EPS) * ln_g[j] + ln_b[j];
        __syncthreads();
        scr[64 + j] = f;
        __syncthreads();

        float a0 = b_ih[j] + b_hh[j];
        float a1 = b_ih[j + 64] + b_hh[j + 64];
        #pragma unroll
        for (int k = 0; k < 64; k++) {
            float fk = scr[64 + k];
            a0 += fk * wihT[k * 128 + j];
            a1 += fk * wihT[k * 128 + 64 + j];
        }
        Gx[t * 128 + j]      = a0;
        Gx[t * 128 + 64 + j] = a1;

        __threadfence();   // make Gx stores agent-visible (proven R2 path)
        __syncthreads();
        if (j == 0)
            __hip_atomic_store(&flags[t], MAGIC, __ATOMIC_RELEASE,
                               __HIP_MEMORY_SCOPE_AGENT);
        return;
    }

    // --------------------------- scan block (1 wave) ---------------------------
    float* gxs = smem;  // [61*128] (frame 60 = pad for prefetch)

    // Stage w_hh -> VGPRs while frontend blocks run (independent of flags).
    v2f wAB[32];
    {
        const float4* r0 = (const float4*)(w_hh + j * 32);
        const float4* r1 = (const float4*)(w_hh + (j + 64) * 32);
        #pragma unroll
        for (int q = 0; q < 8; q++) {
            float4 a = r0[q];
            float4 b = r1[q];
            wAB[4 * q + 0] = (v2f){a.x, b.x};
            wAB[4 * q + 1] = (v2f){a.y, b.y};
            wAB[4 * q + 2] = (v2f){a.z, b.z};
            wAB[4 * q + 3] = (v2f){a.w, b.w};
        }
    }

    // Parallel poll: lane t watches flags[t] (relaxed agent load = L1-bypass,
    // no per-poll fence); one ballot per sweep. Poison 0xAAAAAAAA != MAGIC
    // re-arms every replay.
    {
        bool done = (j >= 60);
        while (true) {
            if (!done)
                done = (__hip_atomic_load(&flags[j], __ATOMIC_RELAXED,
                                          __HIP_MEMORY_SCOPE_AGENT) == MAGIC);
            if (__ballot(done) == ~0ULL) break;
            __builtin_amdgcn_s_sleep(1);
        }
        // single acquire for ordering: Gx reads below must see released data
        (void)__hip_atomic_load(&flags[0], __ATOMIC_ACQUIRE,
                                __HIP_MEMORY_SCOPE_AGENT);
    }

    // stage Gx -> LDS (1920 float4) + zero pad frame
    {
        const float4* g4 = (const float4*)Gx;
        float4* s4 = (float4*)gxs;
        for (int i = j; i < 1920; i += 64) s4[i] = g4[i];
        gxs[7680 + j] = 0.0f;
        gxs[7744 + j] = 0.0f;
    }
    __syncthreads();

    const bool low = (j < 32);
    float c = 0.0f, hn = 0.0f;
    float gA = gxs[j], gB = gxs[64 + j];
    for (int t = 0; t < 60; t++) {
        float hk[32];
        #pragma unroll
        for (int k = 0; k < 32; k++) hk[k] = rdl32(hn, k);

        v2f acc0 = {gA, gB};
        v2f acc1 = {0.f, 0.f};
        v2f acc2 = {0.f, 0.f};
        v2f acc3 = {0.f, 0.f};
        gA = gxs[(t + 1) * 128 + j];
        gB = gxs[(t + 1) * 128 + 64 + j];
        #pragma unroll
        for (int d = 0; d < 8; d++) {
            int k = d * 4;
            v2f h0 = {hk[k + 0], hk[k + 0]};
            v2f h1 = {hk[k + 1], hk[k + 1]};
            v2f h2 = {hk[k + 2], hk[k + 2]};
            v2f h3 = {hk[k + 3], hk[k + 3]};
            acc0 += h0 * wAB[k + 0];
            acc1 += h1 * wAB[k + 1];
            acc2 += h2 * wAB[k + 2];
            acc3 += h3 * wAB[k + 3];
        }
        v2f asum = (acc0 + acc1) + (acc2 + acc3);
        float a0 = asum.x;  // low: i_m ; high: f_m
        float a1 = asum.y;  // low: g_m ; high: o_m

        // shared exp: sigm(a1) and tanh(a1) from one exp(-a1)
        float e1 = __expf(-a1);
        float sO = frcp(1.0f + e1);                 // high: sigm(o)
        float e2 = e1 * e1;                         // exp(-2*a1)
        float t1 = (1.0f - e2) * frcp(1.0f + e2);   // low: tanh(g)
        float s0 = fsigm(a0);                       // low: sigm(i); high: sigm(f)
        float own = s0 * (low ? t1 : c);
        c = xhalf_sum(own);          // sigm(i)tanh(g) + sigm(f)*c, all lanes
        hn = sO * ftanh(c);          // valid on high lanes
    }

    // Head (h read from HIGH lanes; lanes >=32 replicate rows 0..31)
    const float rs = rsqrtf(1.0f + EPS);
    const int ro = j & 31;
    float acc = b10[ro];
    #pragma unroll
    for (int k = 0; k < 32; k++) {
        float hkk = rdl32(hn, k);
        float hb = hkk * rs * bn_g[k] + bn_b[k];
        acc += w10[ro * 32 + k] * hb;
    }
    float o1 = fmaxf(acc, 0.0f);

    acc = b11[ro];
    #pragma unroll
    for (int k = 0; k < 32; k++)
        acc += w11[ro * 32 + k]
             * __int_as_float(__builtin_amdgcn_readlane(__float_as_int(o1), k));
    float o2 = fmaxf(acc, 0.0f);

    float a[4];
    #pragma unroll
    for (int r = 0; r < 4; r++) a[r] = b12[j + 64 * r];
    #pragma unroll
    for (int k = 0; k < 32; k++) {
        float h2 = __int_as_float(__builtin_amdgcn_readlane(__float_as_int(o2), k));
        #pragma unroll
        for (int r = 0; r < 4; r++) a[r] += w12[(j + 64 * r) * 32 + k] * h2;
    }
    #pragma unroll
    for (int r = 0; r < 4; r++) out[j + 64 * r] = a[r];
}

extern "C" void kernel_launch(void* const* d_in, const int* in_sizes, int n_in,
                              void* d_out, int out_size, void* d_ws, size_t ws_size,
                              hipStream_t stream) {
    const float* x    = (const float*)d_in[0];
    const float* w00  = (const float*)d_in[1];
    const float* b00  = (const float*)d_in[2];
    const float* w01  = (const float*)d_in[3];
    const float* b01  = (const float*)d_in[4];
    const float* ln_g = (const float*)d_in[5];
    const float* ln_b = (const float*)d_in[6];
    const float* w_ih = (const float*)d_in[7];
    const float* w_hh = (const float*)d_in[8];
    const float* b_ih = (const float*)d_in[9];
    const float* b_hh = (const float*)d_in[10];
    const float* bn_g = (const float*)d_in[11];
    const float* bn_b = (const float*)d_in[12];
    const float* w10  = (const float*)d_in[13];
    const float* b10  = (const float*)d_in[14];
    const float* w11  = (const float*)d_in[15];
    const float* b11  = (const float*)d_in[16];
    const float* w12  = (const float*)d_in[17];
    const float* b12  = (const float*)d_in[18];
    float* out = (float*)d_out;
    float*    Gx    = (float*)d_ws;                       // 30,720 B
    unsigned* flags = (unsigned*)((char*)d_ws + 49152);   // 60 flags

    fused_kernel<<<61, 64, 0, stream>>>(x, w00, b00, w01, b01, ln_g, ln_b,
                                        w_ih, w_hh, b_ih, b_hh, bn_g, bn_b,
                                        w10, b10, w11, b11, w12, b12,
                                        Gx, flags, out);
}